// Round 6
// baseline (56.343 us; speedup 1.0000x reference)
//
#include <hip/hip_runtime.h>
#include <stdint.h>

// Soft decision-tree ensemble, collapsed to:
//   out[b,c] = sum_t ( A'[t,c] + sum_{k<4} d[b,t,k]*B'[t,k,c] ) / (4 + d[b,t,3] + 1e-8)
//   d[b,t,k] = sigmoid( X[b,:] . W[t,k,:] + bias[t,k] ),  nodes 0..3 only.
// GEMM 65536x512 @ 512x256, memory-bound on X (134 MB fp32 read once).
// R6: kill W's HBM re-fetch (was doubling traffic to ~268MB -> 42us wall).
//     W k-slices go global->REGISTERS (ring-3, L2-hot: all blocks in lockstep).
//     X is the only HBM stream: 64-row blocks, BK=32, reg-hop ring-4 -> LDS f16
//     dbuf, ONE barrier per k-step, compiler-managed waits (2-3 windows slack).

#define KDIM 512
#define PPT 3607

typedef _Float16 f16x4 __attribute__((ext_vector_type(4)));
typedef _Float16 f16x8 __attribute__((ext_vector_type(8)));
typedef float f32x4 __attribute__((ext_vector_type(4)));

// ws layout (bytes):
//   [0, 262144)       Wh   : _Float16 [256 cols][512 k]   (col = t*4 + node)
//   [262144, 263168)  biasN: float[256]
//   [263168, 265728)  AB   : float[64][10]

__global__ __launch_bounds__(128) void prep_kernel(const float* __restrict__ p,
                                                   const float* __restrict__ tw,
                                                   _Float16* __restrict__ Wh,
                                                   float* __restrict__ biasN,
                                                   float* __restrict__ AB) {
    const int c = blockIdx.x;          // 0..255
    const int t = c >> 2, i = c & 3;
    const float* wsrc = p + t * PPT + i * KDIM;
    for (int k = threadIdx.x; k < KDIM; k += 128)
        Wh[c * KDIM + k] = (_Float16)wsrc[k];
    if (threadIdx.x == 0)
        biasN[c] = p[t * PPT + 7 * KDIM + i];
    if (threadIdx.x == 64 && c < 64) {
        const int tt = c;
        const float* lg = p + tt * PPT + 7 * 513;   // leaf logits, 8 x 2
        const float w = tw[tt];
        float ld[8][2];
#pragma unroll
        for (int j = 0; j < 8; ++j) {
            float a = lg[2 * j], b = lg[2 * j + 1];
            float m = fmaxf(a, b);
            float e0 = expf(a - m), e1 = expf(b - m);
            float s = e0 + e1;
            ld[j][0] = e0 / s; ld[j][1] = e1 / s;
        }
        float* o = AB + tt * 10;
#pragma unroll
        for (int cc = 0; cc < 2; ++cc) {
            o[0 + cc] = w * (ld[0][cc] + ld[2][cc] + ld[4][cc] + ld[6][cc]);
            o[2 + cc] = w * (ld[1][cc] - ld[2][cc]);
            o[4 + cc] = w * (ld[3][cc] - ld[4][cc]);
            o[6 + cc] = w * (ld[5][cc] - ld[6][cc]);
            o[8 + cc] = w * (ld[7][cc]);
        }
    }
}

// LDS (40192 B, 2 blocks/CU):
//   xbuf[2]: f16 [64 rows][40 halves] (80 B/row, 16B-aligned) at b*5120
//            16B-granule swizzle: phys g' = g ^ (row&3)  (g = 0..3 real granules)
//   epilogue overlay (loop-dead): E f32 [32][260] at 0 (33280 B)
//   AB f32[640] at 33280;  P f32 [32][34] at 35840 (4352 B) -> 40192 total
#define XB_STRIDE 5120
#define ROWB 80
#define EPI_S 260
#define AB_OFF 33280
#define P_OFF 35840
#define P_S 34
#define LDS_BYTES 40192

__device__ __forceinline__ f16x4 cvt4(float4 a) {
    f16x4 h;
    h[0] = (_Float16)a.x; h[1] = (_Float16)a.y;
    h[2] = (_Float16)a.z; h[3] = (_Float16)a.w;
    return h;
}

__global__ __launch_bounds__(512, 4) void main_kernel(const float* __restrict__ X,
                                                      const _Float16* __restrict__ Wh,
                                                      const float* __restrict__ biasN,
                                                      const float* __restrict__ ABg,
                                                      float* __restrict__ out) {
    extern __shared__ char smem[];
    const int tid = threadIdx.x;
    const int lane = tid & 63;
    const int w = tid >> 6;          // wave 0..7 : owns cols w*32 .. +31
    const int r15 = lane & 15;
    const int hi = lane >> 4;        // 0..3
    const int gr0 = blockIdx.x * 64; // 64 rows per block

    // AB coeffs -> LDS (region untouched by the loop)
    {
        float* abl = (float*)(smem + AB_OFF);
        for (int i = tid; i < 640; i += 512) abl[i] = ABg[i];
    }

    // ---- X staging map: thread owns row = tid>>3, 4-float quad q = tid&7 ----
    const int xrow = tid >> 3, xq = tid & 7;
    const float* Xp = X + (size_t)(gr0 + xrow) * KDIM + xq * 4;
    const int xw = xrow * ROWB + ((((xq >> 1) ^ (xrow & 3))) << 4) + ((xq & 1) << 3);

    // ---- W direct-to-reg addresses (B-frag: col = w*32 + ct*16 + r15, k = hi*8..) ----
    const _Float16* Wc0 = Wh + (size_t)(w * 32 + r15) * KDIM + hi * 8;
    const _Float16* Wc1 = Wh + (size_t)(w * 32 + 16 + r15) * KDIM + hi * 8;

    float bl[2];
    bl[0] = biasN[w * 32 + r15];
    bl[1] = biasN[w * 32 + 16 + r15];

    // A-frag read offset: row = rt*16 + r15; byte = row*80 + ((hi ^ (row&3))<<4)
    const int aoff = r15 * ROWB + ((hi ^ (r15 & 3)) << 4);   // + rt*1280

    f32x4 acc[4][2];
#pragma unroll
    for (int rt = 0; rt < 4; ++rt)
#pragma unroll
        for (int ct = 0; ct < 2; ++ct)
            acc[rt][ct] = (f32x4){0.f, 0.f, 0.f, 0.f};

    float4 xr[4];
    f16x8 Wf[3][2];

    // ---- prologue: X0 (temp, staged now), W0, W1, X1, X2 ----
    {
        float4 x0 = *(const float4*)(Xp);
        Wf[0][0] = *(const f16x8*)(Wc0);
        Wf[0][1] = *(const f16x8*)(Wc1);
        xr[1] = *(const float4*)(Xp + 32);
        Wf[1][0] = *(const f16x8*)(Wc0 + 32);
        Wf[1][1] = *(const f16x8*)(Wc1 + 32);
        xr[2] = *(const float4*)(Xp + 64);
        *(f16x4*)(smem + xw) = cvt4(x0);      // compiler waits precisely on x0
    }
    asm volatile("s_waitcnt lgkmcnt(0)" ::: "memory");
    __builtin_amdgcn_s_barrier();             // xbuf0 certified

#pragma unroll
    for (int kt = 0; kt < 16; ++kt) {
        // issue X(kt+3) (HBM, ~3 windows of slack)
        if (kt <= 12)
            xr[(kt + 3) & 3] = *(const float4*)(Xp + (size_t)(kt + 3) * 32);
        // issue W(kt+2) (L2-hot, 2 windows of slack)
        if (kt <= 13) {
            Wf[(kt + 2) % 3][0] = *(const f16x8*)(Wc0 + (size_t)(kt + 2) * 32);
            Wf[(kt + 2) % 3][1] = *(const f16x8*)(Wc1 + (size_t)(kt + 2) * 32);
        }
        // stage X(kt+1) -> xbuf[(kt+1)&1] (readers this window use xbuf[kt&1])
        if (kt <= 14)
            *(f16x4*)(smem + ((kt + 1) & 1) * XB_STRIDE + xw) = cvt4(xr[(kt + 1) & 3]);
        // compute step kt from xbuf[kt&1] + Wf[kt%3]
        {
            const char* xb = smem + (kt & 1) * XB_STRIDE;
#pragma unroll
            for (int rt = 0; rt < 4; ++rt) {
                f16x8 a = *(const f16x8*)(xb + rt * 1280 + aoff);
                acc[rt][0] = __builtin_amdgcn_mfma_f32_16x16x32_f16(a, Wf[kt % 3][0], acc[rt][0], 0, 0, 0);
                acc[rt][1] = __builtin_amdgcn_mfma_f32_16x16x32_f16(a, Wf[kt % 3][1], acc[rt][1], 0, 0, 0);
            }
        }
        asm volatile("s_waitcnt lgkmcnt(0)" ::: "memory");
        __builtin_amdgcn_s_barrier();          // end of window kt
    }

    // ---- epilogue: 2 passes of 32 rows; E overlays the dead xbuf region ----
    for (int p = 0; p < 2; ++p) {
        float* Ef = (float*)smem;
#pragma unroll
        for (int rt2 = 0; rt2 < 2; ++rt2) {
            const int rt = p * 2 + rt2;
#pragma unroll
            for (int ct = 0; ct < 2; ++ct) {
                const int col = w * 32 + ct * 16 + r15;
#pragma unroll
                for (int reg = 0; reg < 4; ++reg) {
                    const int rowl = rt2 * 16 + hi * 4 + reg;
                    float z = acc[rt][ct][reg] + bl[ct];
                    Ef[rowl * EPI_S + col] = __builtin_amdgcn_rcpf(1.f + __expf(-z));
                }
            }
        }
        asm volatile("s_waitcnt lgkmcnt(0)" ::: "memory");
        __builtin_amdgcn_s_barrier();
        {   // reduce: thread -> row = tid>>4 (32 rows), tree-group tg = tid&15 (4 trees)
            const float* abl = (const float*)(smem + AB_OFF);
            float* Pf = (float*)(smem + P_OFF);
            const int row = tid >> 4, tg = tid & 15;
            float s0 = 0.f, s1 = 0.f;
#pragma unroll
            for (int j = 0; j < 4; ++j) {
                const int t = tg * 4 + ((j + tg) & 3);   // rotation spreads E banks
                float4 dv = *(const float4*)&Ef[row * EPI_S + t * 4];
                const float* abt = &abl[t * 10];
                float inv = __builtin_amdgcn_rcpf(4.f + dv.w + 1e-8f);
                s0 += (abt[0] + dv.x * abt[2] + dv.y * abt[4] + dv.z * abt[6] + dv.w * abt[8]) * inv;
                s1 += (abt[1] + dv.x * abt[3] + dv.y * abt[5] + dv.z * abt[7] + dv.w * abt[9]) * inv;
            }
            Pf[row * P_S + tg * 2 + 0] = s0;
            Pf[row * P_S + tg * 2 + 1] = s1;
        }
        asm volatile("s_waitcnt lgkmcnt(0)" ::: "memory");
        __builtin_amdgcn_s_barrier();
        if (tid < 64) {
            const float* Pf = (const float*)(smem + P_OFF);
            const int row = tid >> 1, c = tid & 1;
            float s = 0.f;
#pragma unroll
            for (int tg = 0; tg < 16; ++tg) s += Pf[row * P_S + tg * 2 + c];
            out[(size_t)(gr0 + p * 32 + row) * 2 + c] = s;
        }
        // pass-1 E writes are safe: all pass-0 E reads completed before the
        // post-reduce barrier; final P-read and pass-1 E-write touch disjoint LDS.
    }
}

extern "C" void kernel_launch(void* const* d_in, const int* in_sizes, int n_in,
                              void* d_out, int out_size, void* d_ws, size_t ws_size,
                              hipStream_t stream) {
    const float* x  = (const float*)d_in[0];
    const float* tp = (const float*)d_in[1];
    const float* tw = (const float*)d_in[2];
    float* out = (float*)d_out;

    _Float16* Wh = (_Float16*)d_ws;
    float* biasN = (float*)((char*)d_ws + 262144);
    float* AB    = (float*)((char*)d_ws + 263168);

    (void)hipFuncSetAttribute((const void*)reinterpret_cast<const void*>(&main_kernel),
                              hipFuncAttributeMaxDynamicSharedMemorySize, LDS_BYTES);

    prep_kernel<<<256, 128, 0, stream>>>(tp, tw, Wh, biasN, AB);
    main_kernel<<<1024, 512, LDS_BYTES, stream>>>(x, Wh, biasN, AB, out);
}

// Round 7
// 51.002 us; speedup vs baseline: 1.1047x; 1.1047x over previous
//
#include <hip/hip_runtime.h>
#include <stdint.h>

// Soft decision-tree ensemble, collapsed to:
//   out[b,c] = sum_t ( A'[t,c] + sum_{k<4} d[b,t,k]*B'[t,k,c] ) / (4 + d[b,t,3] + 1e-8)
//   d[b,t,k] = sigmoid( X[b,:] . W[t,k,:] + bias[t,k] ),  nodes 0..3 only.
// GEMM 65536x512 @ 512x256, memory-bound on X (134 MB fp32 read once).
// R7 = R2 skeleton + ONE mechanism change: X loads are NON-TEMPORAL (no L2
// allocation) via reg-hop, so W's 256 KB panel stays L2-resident and its
// per-block re-reads stop hitting HBM (was doubling traffic to ~268 MB).
// X: NT float4 x2 -> cvt f16 -> ds_write (ring-2, issued 2 steps ahead).
// W: global_load_lds f16 (caches in L2), double-buffer, counted vmcnt.

#define KDIM 512
#define PPT 3607

typedef _Float16 f16x8 __attribute__((ext_vector_type(8)));
typedef float f32x4 __attribute__((ext_vector_type(4)));

// ws layout (bytes):
//   [0, 262144)       Wh   : _Float16 [256 cols][512 k]   (col = t*4 + node)
//   [262144, 263168)  biasN: float[256]
//   [263168, 265728)  AB   : float[64][10]

__global__ __launch_bounds__(128) void prep_kernel(const float* __restrict__ p,
                                                   const float* __restrict__ tw,
                                                   _Float16* __restrict__ Wh,
                                                   float* __restrict__ biasN,
                                                   float* __restrict__ AB) {
    const int c = blockIdx.x;          // 0..255
    const int t = c >> 2, i = c & 3;
    const float* wsrc = p + t * PPT + i * KDIM;
    for (int k = threadIdx.x; k < KDIM; k += 128)
        Wh[c * KDIM + k] = (_Float16)wsrc[k];
    if (threadIdx.x == 0)
        biasN[c] = p[t * PPT + 7 * KDIM + i];
    if (threadIdx.x == 64 && c < 64) {
        const int tt = c;
        const float* lg = p + tt * PPT + 7 * 513;   // leaf logits, 8 x 2
        const float w = tw[tt];
        float ld[8][2];
#pragma unroll
        for (int j = 0; j < 8; ++j) {
            float a = lg[2 * j], b = lg[2 * j + 1];
            float m = fmaxf(a, b);
            float e0 = expf(a - m), e1 = expf(b - m);
            float s = e0 + e1;
            ld[j][0] = e0 / s; ld[j][1] = e1 / s;
        }
        float* o = AB + tt * 10;
#pragma unroll
        for (int cc = 0; cc < 2; ++cc) {
            o[0 + cc] = w * (ld[0][cc] + ld[2][cc] + ld[4][cc] + ld[6][cc]);
            o[2 + cc] = w * (ld[1][cc] - ld[2][cc]);
            o[4 + cc] = w * (ld[3][cc] - ld[4][cc]);
            o[6 + cc] = w * (ld[5][cc] - ld[6][cc]);
            o[8 + cc] = w * (ld[7][cc]);
        }
    }
}

// LDS map (73216 B / block, 2 blocks/CU):
//   xbuf[2]: f16 [128 rows][32 k] at b*8192 (8 KiB each)
//            16B-granule swizzle within row: g' = g ^ (row&3)   (4 granules/row)
//   wbuf[2]: f16 [256 cols][32 k] at 16384 + b*16384 (16 KiB each)
//            k-swizzle: k' = k ^ (((col>>1)&3)<<3)  (8-half granule) [R2-verified]
//   epilogue overlay (loop-dead): E f32 [64][260] at 0 (66560 B)
//   AB f32[640] at 66560;  P f32 [8][64][2] at 69120 (4096 B)
#define XB_STRIDE 8192
#define WB_BASE 16384
#define WB_STRIDE 16384
#define EPI_S 260
#define AB_OFF 66560
#define P_OFF 69120
#define LDS_BYTES 73216

__device__ __forceinline__ void gll16(const void* g, void* l) {
    __builtin_amdgcn_global_load_lds((const __attribute__((address_space(1))) uint32_t*)g,
                                     (__attribute__((address_space(3))) uint32_t*)l, 16, 0, 0);
}

__device__ __forceinline__ f16x8 cvt8(f32x4 a, f32x4 b) {
    f16x8 h;
    h[0] = (_Float16)a.x; h[1] = (_Float16)a.y; h[2] = (_Float16)a.z; h[3] = (_Float16)a.w;
    h[4] = (_Float16)b.x; h[5] = (_Float16)b.y; h[6] = (_Float16)b.z; h[7] = (_Float16)b.w;
    return h;
}

__global__ __launch_bounds__(512, 4) void main_kernel(const float* __restrict__ X,
                                                      const _Float16* __restrict__ Wh,
                                                      const float* __restrict__ biasN,
                                                      const float* __restrict__ ABg,
                                                      float* __restrict__ out) {
    extern __shared__ char smem[];
    const int tid = threadIdx.x;
    const int lane = tid & 63;
    const int w = tid >> 6;          // wave 0..7
    const int wm = w >> 2;           // 0..1 : 64-row half
    const int wn = w & 3;            // 0..3 : 64-col quarter
    const int r15 = lane & 15;
    const int hi = lane >> 4;        // 0..3
    const int gr0 = blockIdx.x * 128;

    // AB coeffs -> LDS (region untouched by staging); then clean vmcnt slate
    {
        float* abl = (float*)(smem + AB_OFF);
        for (int i = tid; i < 640; i += 512) abl[i] = ABg[i];
    }
    asm volatile("s_waitcnt vmcnt(0)" ::: "memory");

    // ---- X staging: thread owns row = tid>>2, k-chunk xg = tid&3 (8 floats) ----
    const int xrow = tid >> 2, xg = tid & 3;
    const float* Xp = X + (size_t)(gr0 + xrow) * KDIM + xg * 8;
    const int xw = xrow * 64 + ((xg ^ (xrow & 3)) << 4);     // byte offset in xbuf

    // ---- W staging (gll, pre-swizzled source) [R2 verbatim] ----
    const _Float16* srcW[2];
    int dW[2];
#pragma unroll
    for (int i = 0; i < 2; ++i) {
        int colW = i * 128 + w * 16 + (lane >> 2);            // 0..255
        int kW = ((lane & 3) << 3) ^ (((colW >> 1) & 3) << 3);
        srcW[i] = Wh + (size_t)colW * KDIM + kW;
        dW[i] = (i * 512 + w * 64 + lane) * 16;               // bytes within wbuf
    }

    // fragment-read constants
    const int kb = (lane >> 4) << 3;                          // k-quarter * 8 halves
    const int kws = kb ^ (((lane >> 1) & 3) << 3);            // W swizzled k (halves)
    const int bColBase = (wn * 64 + r15) * 32;                // W col * 32 halves
    const int aoff = (wm * 64 + r15) * 64 + ((hi ^ (r15 & 3)) << 4);  // + rt*1024 bytes

    f32x4 acc[4][4];
#pragma unroll
    for (int rt = 0; rt < 4; ++rt)
#pragma unroll
        for (int nt = 0; nt < 4; ++nt)
            acc[rt][nt] = (f32x4){0.f, 0.f, 0.f, 0.f};

    f32x4 xr[2][2];

    // ---- prologue: X0(NT), W0(gll), X1(NT); stage X0 ----
    {
        xr[0][0] = __builtin_nontemporal_load((const f32x4*)(Xp));
        xr[0][1] = __builtin_nontemporal_load((const f32x4*)(Xp + 4));
        gll16(srcW[0], smem + WB_BASE + dW[0]);
        gll16(srcW[1], smem + WB_BASE + dW[1]);
        xr[1][0] = __builtin_nontemporal_load((const f32x4*)(Xp + 32));
        xr[1][1] = __builtin_nontemporal_load((const f32x4*)(Xp + 32 + 4));
        // compiler waits precisely on X0 regs (leaves W0, X1 in flight)
        *(f16x8*)(smem + xw) = cvt8(xr[0][0], xr[0][1]);
    }

#pragma unroll
    for (int kt = 0; kt < 16; ++kt) {
        // a: issue X(kt+2) NT into reg slot kt&1 (its old content consumed)
        if (kt <= 13) {
            xr[kt & 1][0] = __builtin_nontemporal_load((const f32x4*)(Xp + (size_t)(kt + 2) * 32));
            xr[kt & 1][1] = __builtin_nontemporal_load((const f32x4*)(Xp + (size_t)(kt + 2) * 32 + 4));
        }
        // barrier #1: all waves done READING the buffers we're about to refill
        __builtin_amdgcn_s_barrier();
        // b: W(kt+1) gll -> wbuf[(kt+1)&1]
        if (kt <= 14) {
            char* wb = smem + WB_BASE + ((kt + 1) & 1) * WB_STRIDE;
            gll16(srcW[0] + (size_t)(kt + 1) * 32, wb + dW[0]);
            gll16(srcW[1] + (size_t)(kt + 1) * 32, wb + dW[1]);
        }
        // c: cvt + ds_write X(kt+1) (loaded 2 steps ago) -> xbuf[(kt+1)&1]
        if (kt <= 14)
            *(f16x8*)(smem + ((kt + 1) & 1) * XB_STRIDE + xw) =
                cvt8(xr[(kt + 1) & 1][0], xr[(kt + 1) & 1][1]);
        // d: counted wait certifies W(kt) (issued last iter); keeps {X(kt+2), W(kt+1)} in flight
        if (kt <= 13)      asm volatile("s_waitcnt vmcnt(4)" ::: "memory");
        else if (kt == 14) asm volatile("s_waitcnt vmcnt(2)" ::: "memory");
        else               asm volatile("s_waitcnt vmcnt(0)" ::: "memory");
        asm volatile("s_waitcnt lgkmcnt(0)" ::: "memory");    // my ds_write committed
        // barrier #2: tile kt fully staged for all waves
        __builtin_amdgcn_s_barrier();
        // f: compute step kt from xbuf[kt&1], wbuf[kt&1]
        {
            const char* xb = smem + (kt & 1) * XB_STRIDE;
            const _Float16* Wl = (const _Float16*)(smem + WB_BASE + (kt & 1) * WB_STRIDE);
            f16x8 bfr[4];
#pragma unroll
            for (int nt = 0; nt < 4; ++nt)
                bfr[nt] = *(const f16x8*)&Wl[bColBase + nt * 512 + kws];
#pragma unroll
            for (int rt = 0; rt < 4; ++rt) {
                f16x8 af = *(const f16x8*)(xb + aoff + rt * 1024);
#pragma unroll
                for (int nt = 0; nt < 4; ++nt)
                    acc[rt][nt] = __builtin_amdgcn_mfma_f32_16x16x32_f16(af, bfr[nt], acc[rt][nt], 0, 0, 0);
            }
        }
    }

    // ---- epilogue: 2 passes of 64 rows, transpose via LDS overlay [R2 verbatim] ----
    __syncthreads();   // all compute reads done before overlaying staging region

    for (int p = 0; p < 2; ++p) {
        if (wm == p) {
            float bl[4];
#pragma unroll
            for (int nt = 0; nt < 4; ++nt) bl[nt] = biasN[wn * 64 + nt * 16 + r15];
            float* ep = (float*)smem;
#pragma unroll
            for (int rt = 0; rt < 4; ++rt)
#pragma unroll
                for (int nt = 0; nt < 4; ++nt) {
                    const int col = wn * 64 + nt * 16 + r15;
#pragma unroll
                    for (int reg = 0; reg < 4; ++reg) {
                        const int rowl = rt * 16 + hi * 4 + reg;
                        float z = acc[rt][nt][reg] + bl[nt];
                        ep[rowl * EPI_S + col] = __builtin_amdgcn_rcpf(1.f + __expf(-z));
                    }
                }
        }
        __syncthreads();
        {   // all 8 waves: wave w sums trees w*8..w*8+7 for all 64 rows (lane = row)
            const float* ep = (const float*)smem;
            const float* abl = (const float*)(smem + AB_OFF);
            float* pb = (float*)(smem + P_OFF);
            const int r = lane;
            float s0 = 0.f, s1 = 0.f;
#pragma unroll
            for (int j = 0; j < 8; ++j) {
                const int t = w * 8 + j;
                float4 dv = *(const float4*)&ep[r * EPI_S + t * 4];
                const float* abt = &abl[t * 10];
                float inv = __builtin_amdgcn_rcpf(4.f + dv.w + 1e-8f);
                s0 += (abt[0] + dv.x * abt[2] + dv.y * abt[4] + dv.z * abt[6] + dv.w * abt[8]) * inv;
                s1 += (abt[1] + dv.x * abt[3] + dv.y * abt[5] + dv.z * abt[7] + dv.w * abt[9]) * inv;
            }
            pb[(w * 64 + r) * 2 + 0] = s0;
            pb[(w * 64 + r) * 2 + 1] = s1;
        }
        __syncthreads();
        if (tid < 128) {
            const float* pb = (const float*)(smem + P_OFF);
            const int r = tid >> 1, c = tid & 1;
            float s = 0.f;
#pragma unroll
            for (int g = 0; g < 8; ++g) s += pb[(g * 64 + r) * 2 + c];
            out[(size_t)(gr0 + p * 64 + r) * 2 + c] = s;
        }
        if (p == 0) __syncthreads();
    }
}

extern "C" void kernel_launch(void* const* d_in, const int* in_sizes, int n_in,
                              void* d_out, int out_size, void* d_ws, size_t ws_size,
                              hipStream_t stream) {
    const float* x  = (const float*)d_in[0];
    const float* tp = (const float*)d_in[1];
    const float* tw = (const float*)d_in[2];
    float* out = (float*)d_out;

    _Float16* Wh = (_Float16*)d_ws;
    float* biasN = (float*)((char*)d_ws + 262144);
    float* AB    = (float*)((char*)d_ws + 263168);

    (void)hipFuncSetAttribute((const void*)reinterpret_cast<const void*>(&main_kernel),
                              hipFuncAttributeMaxDynamicSharedMemorySize, LDS_BYTES);

    prep_kernel<<<256, 128, 0, stream>>>(tp, tw, Wh, biasN, AB);
    main_kernel<<<512, 512, LDS_BYTES, stream>>>(x, Wh, biasN, AB, out);
}